// Round 2
// baseline (1578.619 us; speedup 1.0000x reference)
//
#include <hip/hip_runtime.h>

#define N_NODES 50000
#define N_EDGES 1600000
#define D_NODE  256
#define D_EDGE  64
#define H       128
#define D_OUT   256

typedef __attribute__((ext_vector_type(8))) short bf16x8;
typedef __attribute__((ext_vector_type(4))) float f32x4;
typedef __attribute__((ext_vector_type(4))) unsigned short u16x4;

__device__ __forceinline__ float bf2f(unsigned short u) {
    union { unsigned int i; float f; } v; v.i = ((unsigned int)u) << 16; return v.f;
}
__device__ __forceinline__ unsigned short f2bf(float f) {
    union { float f; unsigned int i; } v; v.f = f;
    unsigned int r = v.i + 0x7FFFu + ((v.i >> 16) & 1u);
    return (unsigned short)(r >> 16);
}

// K0: convert fp32 weights to bf16 tables in workspace.
// blocks 0..31 -> Wn (32768), 32..39 -> We (8192), 40..103 -> Wr (65536)
__global__ __launch_bounds__(256) void cvt_kernel(
        const float* __restrict__ Wn, const float* __restrict__ We,
        const float* __restrict__ Wr,
        unsigned short* __restrict__ Wn_b, unsigned short* __restrict__ We_b,
        unsigned short* __restrict__ Wr_b) {
    int b = blockIdx.x;
    const float* s; unsigned short* d; int base;
    if (b < 32)      { s = Wn; d = Wn_b; base = b * 1024; }
    else if (b < 40) { s = We; d = We_b; base = (b - 32) * 1024; }
    else             { s = Wr; d = Wr_b; base = (b - 40) * 1024; }
    int i = base + threadIdx.x * 4;
    f32x4 v = *(const f32x4*)(s + i);
    u16x4 o;
    #pragma unroll
    for (int j = 0; j < 4; ++j) o[j] = f2bf(v[j]);
    *(u16x4*)(d + i) = o;
}

// K1: hn = x @ Wn^T + bn   -> bf16 [N_NODES, H]
// one wave per 16 node rows; 8 o-tiles of 16; K=256 in 8 steps of 32.
__global__ __launch_bounds__(64) void hn_kernel(
        const float* __restrict__ x,
        const unsigned short* __restrict__ Wn_b,
        const float* __restrict__ bn,
        unsigned short* __restrict__ hn) {
    const int lane = threadIdx.x & 63;
    const int m = lane & 15, q = lane >> 4;
    const int n0 = blockIdx.x * 16;

    f32x4 acc[8];
    #pragma unroll
    for (int t = 0; t < 8; ++t)
        #pragma unroll
        for (int r = 0; r < 4; ++r) acc[t][r] = 0.0f;

    const float* xrow = x + (size_t)(n0 + m) * D_NODE + q * 8;
    #pragma unroll
    for (int kk = 0; kk < 8; ++kk) {
        f32x4 a0 = *(const f32x4*)(xrow + kk * 32);
        f32x4 a1 = *(const f32x4*)(xrow + kk * 32 + 4);
        bf16x8 a;
        #pragma unroll
        for (int j = 0; j < 4; ++j) {
            a[j]     = (short)f2bf(a0[j]);
            a[4 + j] = (short)f2bf(a1[j]);
        }
        #pragma unroll
        for (int t = 0; t < 8; ++t) {
            bf16x8 b = *(const bf16x8*)(Wn_b + (size_t)(t * 16 + m) * D_NODE + kk * 32 + q * 8);
            acc[t] = __builtin_amdgcn_mfma_f32_16x16x32_bf16(a, b, acc[t], 0, 0, 0);
        }
    }
    // C/D layout: col = lane&15 (o), row = q*4+reg (node)
    #pragma unroll
    for (int t = 0; t < 8; ++t) {
        int o = t * 16 + m;
        float bv = bn[o];
        #pragma unroll
        for (int r = 0; r < 4; ++r) {
            int node = n0 + q * 4 + r;
            hn[(size_t)node * H + o] = f2bf(acc[t][r] + bv);
        }
    }
}

// K2: per-edge scatter. One wave per edge.
// sumEZ[dst] += ez[e] (64 f32), sumN[dst] += hn[src] (128 f32), deg[dst] += 1
__global__ __launch_bounds__(256) void edge_kernel(
        const int* __restrict__ src, const int* __restrict__ dst,
        const float* __restrict__ ez,
        const unsigned short* __restrict__ hn,
        float* __restrict__ sumN, float* __restrict__ sumEZ,
        unsigned int* __restrict__ deg) {
    int e = blockIdx.x * 4 + (threadIdx.x >> 6);
    e = __builtin_amdgcn_readfirstlane(e);
    const int lane = threadIdx.x & 63;
    const int s = src[e];
    const int d = dst[e];

    float v = ez[(size_t)e * D_EDGE + lane];
    unsafeAtomicAdd(&sumEZ[(size_t)d * D_EDGE + lane], v);

    float h0 = bf2f(hn[(size_t)s * H + lane]);
    float h1 = bf2f(hn[(size_t)s * H + 64 + lane]);
    unsafeAtomicAdd(&sumN[(size_t)d * H + lane], h0);
    unsafeAtomicAdd(&sumN[(size_t)d * H + 64 + lane], h1);

    if (lane == 0) atomicAdd(&deg[d], 1u);
}

// K3: per-16-node tile: build mean_state (bf16, LDS) then out = ms @ Wr^T + br.
__global__ __launch_bounds__(256) void out_kernel(
        const unsigned short* __restrict__ hn,
        const float* __restrict__ sumN,
        const float* __restrict__ sumEZ,
        const unsigned int* __restrict__ deg,
        const unsigned short* __restrict__ We_b,
        const float* __restrict__ be,
        const unsigned short* __restrict__ Wr_b,
        const float* __restrict__ br,
        float* __restrict__ out) {
    __shared__ __align__(16) unsigned short ms[16][264];  // +8 pad
    __shared__ float rden[16];
    __shared__ float degf[16];

    const int t = threadIdx.x;
    const int n0 = blockIdx.x * 16;

    if (t < 16) {
        unsigned int dg = deg[n0 + t];
        degf[t] = (float)dg;
        rden[t] = 1.0f / (1.0f + (float)dg);
    }
    __syncthreads();

    // node half: ms[:, :128] = (hn + sumN) * rden
    {
        int r = t >> 4, c8 = (t & 15) * 8;
        const unsigned short* hp = hn + (size_t)(n0 + r) * H + c8;
        const float* sp = sumN + (size_t)(n0 + r) * H + c8;
        bf16x8 hv = *(const bf16x8*)hp;
        f32x4 s0 = *(const f32x4*)sp;
        f32x4 s1 = *(const f32x4*)(sp + 4);
        float rd = rden[r];
        bf16x8 o;
        #pragma unroll
        for (int j = 0; j < 4; ++j)
            o[j] = (short)f2bf((bf2f((unsigned short)hv[j]) + s0[j]) * rd);
        #pragma unroll
        for (int j = 0; j < 4; ++j)
            o[4 + j] = (short)f2bf((bf2f((unsigned short)hv[4 + j]) + s1[j]) * rd);
        *(bf16x8*)&ms[r][c8] = o;
    }

    // edge half: ms[:, 128:256] = (sumEZ @ We^T + deg*be) * rden via MFMA
    {
        const int w = t >> 6, lane = t & 63;
        const int m = lane & 15, q = lane >> 4;
        f32x4 acc[2];
        #pragma unroll
        for (int i = 0; i < 2; ++i)
            #pragma unroll
            for (int r = 0; r < 4; ++r) acc[i][r] = 0.0f;

        #pragma unroll
        for (int kk = 0; kk < 2; ++kk) {
            const float* ap = sumEZ + (size_t)(n0 + m) * D_EDGE + kk * 32 + q * 8;
            f32x4 a0 = *(const f32x4*)ap;
            f32x4 a1 = *(const f32x4*)(ap + 4);
            bf16x8 a;
            #pragma unroll
            for (int j = 0; j < 4; ++j) {
                a[j]     = (short)f2bf(a0[j]);
                a[4 + j] = (short)f2bf(a1[j]);
            }
            #pragma unroll
            for (int i = 0; i < 2; ++i) {
                int o0 = (w + 4 * i) * 16;
                bf16x8 b = *(const bf16x8*)(We_b + (size_t)(o0 + m) * D_EDGE + kk * 32 + q * 8);
                acc[i] = __builtin_amdgcn_mfma_f32_16x16x32_bf16(a, b, acc[i], 0, 0, 0);
            }
        }
        #pragma unroll
        for (int i = 0; i < 2; ++i) {
            int o = (w + 4 * i) * 16 + m;
            float bev = be[o];
            #pragma unroll
            for (int r = 0; r < 4; ++r) {
                int nl = q * 4 + r;
                float val = (acc[i][r] + degf[nl] * bev) * rden[nl];
                ms[nl][128 + o] = f2bf(val);
            }
        }
    }
    __syncthreads();

    // main GEMM: out = ms @ Wr^T + br ; zero rows with deg==0
    {
        const int w = t >> 6, lane = t & 63;
        const int m = lane & 15, q = lane >> 4;
        f32x4 acc[4];
        #pragma unroll
        for (int i = 0; i < 4; ++i)
            #pragma unroll
            for (int r = 0; r < 4; ++r) acc[i][r] = 0.0f;

        #pragma unroll
        for (int kk = 0; kk < 8; ++kk) {
            bf16x8 a = *(const bf16x8*)&ms[m][kk * 32 + q * 8];
            #pragma unroll
            for (int i = 0; i < 4; ++i) {
                int o0 = (w * 4 + i) * 16;
                bf16x8 b = *(const bf16x8*)(Wr_b + (size_t)(o0 + m) * 256 + kk * 32 + q * 8);
                acc[i] = __builtin_amdgcn_mfma_f32_16x16x32_bf16(a, b, acc[i], 0, 0, 0);
            }
        }
        #pragma unroll
        for (int i = 0; i < 4; ++i) {
            int o = (w * 4 + i) * 16 + m;
            float brv = br[o];
            #pragma unroll
            for (int r = 0; r < 4; ++r) {
                int nl = q * 4 + r;
                float val = acc[i][r] + brv;
                if (degf[nl] == 0.0f) val = 0.0f;
                out[(size_t)(n0 + nl) * D_OUT + o] = val;
            }
        }
    }
}

extern "C" void kernel_launch(void* const* d_in, const int* in_sizes, int n_in,
                              void* d_out, int out_size, void* d_ws, size_t ws_size,
                              hipStream_t stream) {
    const float* x  = (const float*)d_in[0];
    const float* ez = (const float*)d_in[1];
    const int* src  = (const int*)d_in[2];
    const int* dst  = (const int*)d_in[3];
    const float* Wn = (const float*)d_in[4];
    const float* bn = (const float*)d_in[5];
    const float* We = (const float*)d_in[6];
    const float* be = (const float*)d_in[7];
    const float* Wr = (const float*)d_in[8];
    const float* br = (const float*)d_in[9];
    float* out      = (float*)d_out;

    // workspace layout (all 16B-aligned)
    float* sumN  = (float*)d_ws;                                // N*128 f32 = 25.6 MB
    float* sumEZ = sumN + (size_t)N_NODES * H;                  // N*64  f32 = 12.8 MB
    unsigned int* deg = (unsigned int*)(sumEZ + (size_t)N_NODES * D_EDGE); // N u32
    unsigned short* hn = (unsigned short*)(deg + N_NODES);      // N*128 bf16 = 12.8 MB
    unsigned short* Wn_b = hn + (size_t)N_NODES * H;            // 32768 bf16
    unsigned short* We_b = Wn_b + 32768;                        // 8192 bf16
    unsigned short* Wr_b = We_b + 8192;                         // 65536 bf16

    const size_t zero_bytes = (size_t)N_NODES * H * 4 + (size_t)N_NODES * D_EDGE * 4
                            + (size_t)N_NODES * 4;
    hipMemsetAsync(d_ws, 0, zero_bytes, stream);

    cvt_kernel<<<104, 256, 0, stream>>>(Wn, We, Wr, Wn_b, We_b, Wr_b);
    hn_kernel<<<N_NODES / 16, 64, 0, stream>>>(x, Wn_b, bn, hn);
    edge_kernel<<<N_EDGES / 4, 256, 0, stream>>>(src, dst, ez, hn, sumN, sumEZ, deg);
    out_kernel<<<N_NODES / 16, 256, 0, stream>>>(hn, sumN, sumEZ, deg, We_b, be, Wr_b, br, out);
}

// Round 3
// 897.015 us; speedup vs baseline: 1.7599x; 1.7599x over previous
//
#include <hip/hip_runtime.h>

#define N_NODES 50000
#define N_EDGES 1600000
#define D_NODE  256
#define D_EDGE  64
#define H       128
#define D_OUT   256

#define NPAD    50176   // 196*256, padded node count for scan

typedef __attribute__((ext_vector_type(8))) short bf16x8;
typedef __attribute__((ext_vector_type(4))) float f32x4;
typedef __attribute__((ext_vector_type(4))) unsigned short u16x4;

__device__ __forceinline__ float bf2f(unsigned short u) {
    union { unsigned int i; float f; } v; v.i = ((unsigned int)u) << 16; return v.f;
}
__device__ __forceinline__ unsigned short f2bf(float f) {
    union { float f; unsigned int i; } v; v.f = f;
    unsigned int r = v.i + 0x7FFFu + ((v.i >> 16) & 1u);
    return (unsigned short)(r >> 16);
}

// ---------- K0: convert fp32 weights to bf16 tables ----------
__global__ __launch_bounds__(256) void cvt_kernel(
        const float* __restrict__ Wn, const float* __restrict__ We,
        const float* __restrict__ Wr,
        unsigned short* __restrict__ Wn_b, unsigned short* __restrict__ We_b,
        unsigned short* __restrict__ Wr_b) {
    int b = blockIdx.x;
    const float* s; unsigned short* d; int base;
    if (b < 32)      { s = Wn; d = Wn_b; base = b * 1024; }
    else if (b < 40) { s = We; d = We_b; base = (b - 32) * 1024; }
    else             { s = Wr; d = Wr_b; base = (b - 40) * 1024; }
    int i = base + threadIdx.x * 4;
    f32x4 v = *(const f32x4*)(s + i);
    u16x4 o;
    #pragma unroll
    for (int j = 0; j < 4; ++j) o[j] = f2bf(v[j]);
    *(u16x4*)(d + i) = o;
}

// ---------- K1: hn = x @ Wn^T + bn -> bf16 [N, 128] ----------
__global__ __launch_bounds__(64) void hn_kernel(
        const float* __restrict__ x,
        const unsigned short* __restrict__ Wn_b,
        const float* __restrict__ bn,
        unsigned short* __restrict__ hn) {
    const int lane = threadIdx.x & 63;
    const int m = lane & 15, q = lane >> 4;
    const int n0 = blockIdx.x * 16;

    f32x4 acc[8];
    #pragma unroll
    for (int t = 0; t < 8; ++t)
        #pragma unroll
        for (int r = 0; r < 4; ++r) acc[t][r] = 0.0f;

    const float* xrow = x + (size_t)(n0 + m) * D_NODE + q * 8;
    #pragma unroll
    for (int kk = 0; kk < 8; ++kk) {
        f32x4 a0 = *(const f32x4*)(xrow + kk * 32);
        f32x4 a1 = *(const f32x4*)(xrow + kk * 32 + 4);
        bf16x8 a;
        #pragma unroll
        for (int j = 0; j < 4; ++j) {
            a[j]     = (short)f2bf(a0[j]);
            a[4 + j] = (short)f2bf(a1[j]);
        }
        #pragma unroll
        for (int t = 0; t < 8; ++t) {
            bf16x8 b = *(const bf16x8*)(Wn_b + (size_t)(t * 16 + m) * D_NODE + kk * 32 + q * 8);
            acc[t] = __builtin_amdgcn_mfma_f32_16x16x32_bf16(a, b, acc[t], 0, 0, 0);
        }
    }
    #pragma unroll
    for (int t = 0; t < 8; ++t) {
        int o = t * 16 + m;
        float bv = bn[o];
        #pragma unroll
        for (int r = 0; r < 4; ++r) {
            int node = n0 + q * 4 + r;
            hn[(size_t)node * H + o] = f2bf(acc[t][r] + bv);
        }
    }
}

// ---------- K2a: histogram cnt[dst]++ ----------
__global__ __launch_bounds__(256) void hist_kernel(
        const int* __restrict__ dst, unsigned int* __restrict__ cnt) {
    int e = blockIdx.x * 256 + threadIdx.x;
    atomicAdd(&cnt[dst[e]], 1u);
}

// shfl-based inclusive scan across a 256-thread block; returns inclusive, sets total.
__device__ __forceinline__ unsigned int block_scan_incl(unsigned int v, unsigned int* wtot) {
    const int lane = threadIdx.x & 63;
    const int wid = threadIdx.x >> 6;
    unsigned int x = v;
    #pragma unroll
    for (int off = 1; off < 64; off <<= 1) {
        unsigned int y = __shfl_up(x, off, 64);
        if (lane >= off) x += y;
    }
    if (lane == 63) wtot[wid] = x;
    __syncthreads();
    unsigned int wof = 0;
    #pragma unroll
    for (int w = 0; w < 4; ++w) if (w < wid) wof += wtot[w];
    return x + wof;
}

// ---------- K2b: per-block scan ----------
__global__ __launch_bounds__(256) void scan1_kernel(
        const unsigned int* __restrict__ cnt,
        unsigned int* __restrict__ partial,   // exclusive within block
        unsigned int* __restrict__ blocksum) {
    __shared__ unsigned int wtot[4];
    int i = blockIdx.x * 256 + threadIdx.x;
    unsigned int v = cnt[i];
    unsigned int inc = block_scan_incl(v, wtot);
    partial[i] = inc - v;
    if (threadIdx.x == 255) blocksum[blockIdx.x] = inc;
}

// ---------- K2c: scan the 196 block sums (padded to 256) ----------
__global__ __launch_bounds__(256) void scan2_kernel(
        const unsigned int* __restrict__ blocksum,
        unsigned int* __restrict__ blockoff) {
    __shared__ unsigned int wtot[4];
    unsigned int v = blocksum[threadIdx.x];
    unsigned int inc = block_scan_incl(v, wtot);
    blockoff[threadIdx.x] = inc - v;   // exclusive
}

// ---------- K2d: cursor[i] = global exclusive scan ----------
__global__ __launch_bounds__(256) void cursor_kernel(
        const unsigned int* __restrict__ partial,
        const unsigned int* __restrict__ blockoff,
        unsigned int* __restrict__ cursor) {
    int i = blockIdx.x * 256 + threadIdx.x;
    cursor[i] = partial[i] + blockoff[blockIdx.x];
}

// ---------- K2e: scatter edge ids into dst-bins ----------
__global__ __launch_bounds__(256) void scatter_kernel(
        const int* __restrict__ src, const int* __restrict__ dst,
        unsigned int* __restrict__ cursor,
        unsigned long long* __restrict__ eid_src) {
    int e = blockIdx.x * 256 + threadIdx.x;
    int d = dst[e];
    unsigned int s = (unsigned int)src[e];
    unsigned int pos = atomicAdd(&cursor[d], 1u);
    eid_src[pos] = ((unsigned long long)s << 32) | (unsigned int)e;
}

// ---------- K3: atomic-free aggregation, one wave per node ----------
__global__ __launch_bounds__(256) void agg_kernel(
        const unsigned long long* __restrict__ eid_src,
        const unsigned int* __restrict__ cursor,   // post-scatter == bucket end
        const unsigned int* __restrict__ cnt,
        const float* __restrict__ ez,
        const unsigned int* __restrict__ hn32,
        float* __restrict__ sumN, float* __restrict__ sumEZ) {
    const int n = blockIdx.x * 4 + (threadIdx.x >> 6);
    const int lane = threadIdx.x & 63;
    const unsigned int end = cursor[n];
    const unsigned int c = cnt[n];
    const unsigned int beg = end - c;

    float se = 0.0f, sn0 = 0.0f, sn1 = 0.0f;

    for (unsigned int base = beg; base < end; base += 64) {
        int mcnt = (int)(end - base); if (mcnt > 64) mcnt = 64;
        unsigned long long ent = (lane < mcnt) ? eid_src[base + lane] : 0ULL;
        unsigned int elo = (unsigned int)ent;
        unsigned int shi = (unsigned int)(ent >> 32);

        int j = 0;
        for (; j + 4 <= mcnt; j += 4) {
            unsigned int e0 = __shfl(elo, j, 64),     s0i = __shfl(shi, j, 64);
            unsigned int e1 = __shfl(elo, j + 1, 64), s1i = __shfl(shi, j + 1, 64);
            unsigned int e2 = __shfl(elo, j + 2, 64), s2i = __shfl(shi, j + 2, 64);
            unsigned int e3 = __shfl(elo, j + 3, 64), s3i = __shfl(shi, j + 3, 64);
            float a0 = ez[(size_t)e0 * D_EDGE + lane];
            float a1 = ez[(size_t)e1 * D_EDGE + lane];
            float a2 = ez[(size_t)e2 * D_EDGE + lane];
            float a3 = ez[(size_t)e3 * D_EDGE + lane];
            unsigned int h0 = hn32[(size_t)s0i * 64 + lane];
            unsigned int h1 = hn32[(size_t)s1i * 64 + lane];
            unsigned int h2 = hn32[(size_t)s2i * 64 + lane];
            unsigned int h3 = hn32[(size_t)s3i * 64 + lane];
            se += (a0 + a1) + (a2 + a3);
            union { unsigned int u; float f; } lo, hi;
            lo.u = h0 << 16; hi.u = h0 & 0xffff0000u; sn0 += lo.f; sn1 += hi.f;
            lo.u = h1 << 16; hi.u = h1 & 0xffff0000u; sn0 += lo.f; sn1 += hi.f;
            lo.u = h2 << 16; hi.u = h2 & 0xffff0000u; sn0 += lo.f; sn1 += hi.f;
            lo.u = h3 << 16; hi.u = h3 & 0xffff0000u; sn0 += lo.f; sn1 += hi.f;
        }
        for (; j < mcnt; ++j) {
            unsigned int e0 = __shfl(elo, j, 64), s0i = __shfl(shi, j, 64);
            float a0 = ez[(size_t)e0 * D_EDGE + lane];
            unsigned int h0 = hn32[(size_t)s0i * 64 + lane];
            se += a0;
            union { unsigned int u; float f; } lo, hi;
            lo.u = h0 << 16; hi.u = h0 & 0xffff0000u; sn0 += lo.f; sn1 += hi.f;
        }
    }

    sumEZ[(size_t)n * D_EDGE + lane] = se;
    // lane holds cols 2*lane, 2*lane+1 -> contiguous float2
    float2 p; p.x = sn0; p.y = sn1;
    *((float2*)(sumN + (size_t)n * H) + lane) = p;
}

// ---------- K4: per-16-node tile: mean_state (LDS) then out = ms @ Wr^T + br ----------
__global__ __launch_bounds__(256) void out_kernel(
        const unsigned short* __restrict__ hn,
        const float* __restrict__ sumN,
        const float* __restrict__ sumEZ,
        const unsigned int* __restrict__ deg,
        const unsigned short* __restrict__ We_b,
        const float* __restrict__ be,
        const unsigned short* __restrict__ Wr_b,
        const float* __restrict__ br,
        float* __restrict__ out) {
    __shared__ __align__(16) unsigned short ms[16][264];
    __shared__ float rden[16];
    __shared__ float degf[16];

    const int t = threadIdx.x;
    const int n0 = blockIdx.x * 16;

    if (t < 16) {
        unsigned int dg = deg[n0 + t];
        degf[t] = (float)dg;
        rden[t] = 1.0f / (1.0f + (float)dg);
    }
    __syncthreads();

    // node half: ms[:, :128] = (hn + sumN) * rden
    {
        int r = t >> 4, c8 = (t & 15) * 8;
        const unsigned short* hp = hn + (size_t)(n0 + r) * H + c8;
        const float* sp = sumN + (size_t)(n0 + r) * H + c8;
        bf16x8 hv = *(const bf16x8*)hp;
        f32x4 s0 = *(const f32x4*)sp;
        f32x4 s1 = *(const f32x4*)(sp + 4);
        float rd = rden[r];
        bf16x8 o;
        #pragma unroll
        for (int j = 0; j < 4; ++j)
            o[j] = (short)f2bf((bf2f((unsigned short)hv[j]) + s0[j]) * rd);
        #pragma unroll
        for (int j = 0; j < 4; ++j)
            o[4 + j] = (short)f2bf((bf2f((unsigned short)hv[4 + j]) + s1[j]) * rd);
        *(bf16x8*)&ms[r][c8] = o;
    }

    // edge half: ms[:, 128:256] = (sumEZ @ We^T + deg*be) * rden via MFMA
    {
        const int w = t >> 6, lane = t & 63;
        const int m = lane & 15, q = lane >> 4;
        f32x4 acc[2];
        #pragma unroll
        for (int i = 0; i < 2; ++i)
            #pragma unroll
            for (int r = 0; r < 4; ++r) acc[i][r] = 0.0f;

        #pragma unroll
        for (int kk = 0; kk < 2; ++kk) {
            const float* ap = sumEZ + (size_t)(n0 + m) * D_EDGE + kk * 32 + q * 8;
            f32x4 a0 = *(const f32x4*)ap;
            f32x4 a1 = *(const f32x4*)(ap + 4);
            bf16x8 a;
            #pragma unroll
            for (int j = 0; j < 4; ++j) {
                a[j]     = (short)f2bf(a0[j]);
                a[4 + j] = (short)f2bf(a1[j]);
            }
            #pragma unroll
            for (int i = 0; i < 2; ++i) {
                int o0 = (w + 4 * i) * 16;
                bf16x8 b = *(const bf16x8*)(We_b + (size_t)(o0 + m) * D_EDGE + kk * 32 + q * 8);
                acc[i] = __builtin_amdgcn_mfma_f32_16x16x32_bf16(a, b, acc[i], 0, 0, 0);
            }
        }
        #pragma unroll
        for (int i = 0; i < 2; ++i) {
            int o = (w + 4 * i) * 16 + m;
            float bev = be[o];
            #pragma unroll
            for (int r = 0; r < 4; ++r) {
                int nl = q * 4 + r;
                float val = (acc[i][r] + degf[nl] * bev) * rden[nl];
                ms[nl][128 + o] = f2bf(val);
            }
        }
    }
    __syncthreads();

    // main GEMM: out = ms @ Wr^T + br ; zero rows with deg==0
    {
        const int w = t >> 6, lane = t & 63;
        const int m = lane & 15, q = lane >> 4;
        f32x4 acc[4];
        #pragma unroll
        for (int i = 0; i < 4; ++i)
            #pragma unroll
            for (int r = 0; r < 4; ++r) acc[i][r] = 0.0f;

        #pragma unroll
        for (int kk = 0; kk < 8; ++kk) {
            bf16x8 a = *(const bf16x8*)&ms[m][kk * 32 + q * 8];
            #pragma unroll
            for (int i = 0; i < 4; ++i) {
                int o0 = (w * 4 + i) * 16;
                bf16x8 b = *(const bf16x8*)(Wr_b + (size_t)(o0 + m) * 256 + kk * 32 + q * 8);
                acc[i] = __builtin_amdgcn_mfma_f32_16x16x32_bf16(a, b, acc[i], 0, 0, 0);
            }
        }
        #pragma unroll
        for (int i = 0; i < 4; ++i) {
            int o = (w * 4 + i) * 16 + m;
            float brv = br[o];
            #pragma unroll
            for (int r = 0; r < 4; ++r) {
                int nl = q * 4 + r;
                float val = acc[i][r] + brv;
                if (degf[nl] == 0.0f) val = 0.0f;
                out[(size_t)(n0 + nl) * D_OUT + o] = val;
            }
        }
    }
}

extern "C" void kernel_launch(void* const* d_in, const int* in_sizes, int n_in,
                              void* d_out, int out_size, void* d_ws, size_t ws_size,
                              hipStream_t stream) {
    const float* x  = (const float*)d_in[0];
    const float* ez = (const float*)d_in[1];
    const int* src  = (const int*)d_in[2];
    const int* dst  = (const int*)d_in[3];
    const float* Wn = (const float*)d_in[4];
    const float* bn = (const float*)d_in[5];
    const float* We = (const float*)d_in[6];
    const float* be = (const float*)d_in[7];
    const float* Wr = (const float*)d_in[8];
    const float* br = (const float*)d_in[9];
    float* out      = (float*)d_out;

    // ---- workspace layout (u32 units for the scan arrays) ----
    unsigned int* cnt      = (unsigned int*)d_ws;            // NPAD
    unsigned int* blocksum = cnt + NPAD;                     // 256
    unsigned int* blockoff = blocksum + 256;                 // 256
    unsigned int* partial  = blockoff + 256;                 // NPAD
    unsigned int* cursor   = partial + NPAD;                 // NPAD
    unsigned long long* eid_src = (unsigned long long*)(cursor + NPAD); // N_EDGES u64 (8B aligned)
    float* sumN  = (float*)(eid_src + N_EDGES);              // N*128 f32
    float* sumEZ = sumN + (size_t)N_NODES * H;               // N*64 f32
    unsigned short* hn = (unsigned short*)(sumEZ + (size_t)N_NODES * D_EDGE); // N*128 bf16
    unsigned short* Wn_b = hn + (size_t)N_NODES * H;
    unsigned short* We_b = Wn_b + 32768;
    unsigned short* Wr_b = We_b + 8192;

    // zero only cnt + blocksum (the rest is fully overwritten before any read)
    hipMemsetAsync(d_ws, 0, (size_t)(NPAD + 256) * 4, stream);

    cvt_kernel<<<104, 256, 0, stream>>>(Wn, We, Wr, Wn_b, We_b, Wr_b);
    hn_kernel<<<N_NODES / 16, 64, 0, stream>>>(x, Wn_b, bn, hn);
    hist_kernel<<<N_EDGES / 256, 256, 0, stream>>>(dst, cnt);
    scan1_kernel<<<NPAD / 256, 256, 0, stream>>>(cnt, partial, blocksum);
    scan2_kernel<<<1, 256, 0, stream>>>(blocksum, blockoff);
    cursor_kernel<<<NPAD / 256, 256, 0, stream>>>(partial, blockoff, cursor);
    scatter_kernel<<<N_EDGES / 256, 256, 0, stream>>>(src, dst, cursor, eid_src);
    agg_kernel<<<N_NODES / 4, 256, 0, stream>>>(eid_src, cursor, cnt, ez,
                                                (const unsigned int*)hn, sumN, sumEZ);
    out_kernel<<<N_NODES / 16, 256, 0, stream>>>(hn, sumN, sumEZ, cnt, We_b, be, Wr_b, br, out);
}